// Round 6
// baseline (114.413 us; speedup 1.0000x reference)
//
#include <hip/hip_runtime.h>
#include <math.h>

// Problem constants (match reference)
#define B_SZ   4096
#define NMAX_SZ 64
#define H_SZ   768      // = 3 chunks of 256 floats; lane owns 4 floats per chunk
#define Q_SZ   16384
#define S_SZ   256

// ---------------------------------------------------------------------------
// helpers
// ---------------------------------------------------------------------------
__device__ __forceinline__ float dot12(const float4 a0, const float4 a1, const float4 a2,
                                       const float4 b0, const float4 b1, const float4 b2) {
  float p = a0.x * b0.x + a0.y * b0.y + a0.z * b0.z + a0.w * b0.w;
  p += a1.x * b1.x + a1.y * b1.y + a1.z * b1.z + a1.w * b1.w;
  p += a2.x * b2.x + a2.y * b2.y + a2.z * b2.z + a2.w * b2.w;
  return p;
}

// ---------------------------------------------------------------------------
// Kernel 1: fused attention-pool. One block per b (4096 blocks, 4x resident
// capacity -> HW backfill). Wave w handles rows w, w+4, w+8, ...
// SINGLE accumulator chain with PAIR-MERGED update: both rows' scores are
// reduced (two independent, pipelined shfl chains), then one rescale
// a = a*c + eA*xA + eB*xB. vs dual-chain: -24 VGPRs (no duplicate acc
// state), half the rescale FLOPs. Total loop regs ~90 << the 128 cap from
// __launch_bounds__(256,4) -> spilling is impossible (the suspected ~30%
// tax on all previous variants).
// exp2-domain softmax: qw pre-scaled by log2e per lane, exp2f everywhere
// (identical math to __expf's internals; cross-wave merge also base-2).
// Coalesced chunked lane ownership (lane l owns floats 4l..4l+3 of each
// 256-float chunk): every load is a 1 KB contiguous wave burst.
// One LDS merge + one __syncthreads; wave 0 runs the wm_w epilogue.
// Outputs d1[b]=emb.wm_w[:H], d2[b]=emb.wm_w[H:].
// ---------------------------------------------------------------------------
__global__ __launch_bounds__(256, 4) void merge_dots_kernel(
    const float* __restrict__ padded, const float* __restrict__ qw,
    const float* __restrict__ qb, const float* __restrict__ wmw,
    const int* __restrict__ lengths,
    float* __restrict__ d1, float* __restrict__ d2) {
  const int b = blockIdx.x;
  const int t = threadIdx.x;
  const int lane = t & 63;
  const int w = t >> 6;
  const int len = lengths[b];
  const int o0 = 4 * lane;        // chunk 0 offset
  const int o1 = 256 + 4 * lane;  // chunk 1 offset
  const int o2 = 512 + 4 * lane;  // chunk 2 offset
  const float LOG2E = 1.4426950408889634f;

  __shared__ float sm[4], sl[4];
  __shared__ float sa[12 * 4 * 64];  // [i][w][lane], 12 KB, conflict-free

  // qw pre-scaled by log2e -> scores live in base-2 domain
  float4 q0 = *(const float4*)(qw + o0);
  float4 q1 = *(const float4*)(qw + o1);
  float4 q2 = *(const float4*)(qw + o2);
  q0.x *= LOG2E; q0.y *= LOG2E; q0.z *= LOG2E; q0.w *= LOG2E;
  q1.x *= LOG2E; q1.y *= LOG2E; q1.z *= LOG2E; q1.w *= LOG2E;
  q2.x *= LOG2E; q2.y *= LOG2E; q2.z *= LOG2E; q2.w *= LOG2E;
  const float qb2 = qb[0] * LOG2E;

  const float* base = padded + (size_t)b * (NMAX_SZ * H_SZ);
  const float* wbase = base + w * H_SZ;          // rows w, w+4, ... stride 4*H
  const int cnt = (len > w) ? ((len - w + 3) >> 2) : 0;

  // wave-partial online-softmax state (base-2 domain, unnormalized)
  float m = -INFINITY, l = 0.f;
  float4 a0 = {0, 0, 0, 0}, a1 = {0, 0, 0, 0}, a2 = {0, 0, 0, 0};

  if (cnt > 0) {
    // current pair (k=0 valid; k=1 clamped if cnt==1)
    const float* rA = wbase;
    const float* rB = wbase + (size_t)((1 < cnt) ? 1 : 0) * 4 * H_SZ;
    float4 xA0 = *(const float4*)(rA + o0);
    float4 xA1 = *(const float4*)(rA + o1);
    float4 xA2 = *(const float4*)(rA + o2);
    float4 xB0 = *(const float4*)(rB + o0);
    float4 xB1 = *(const float4*)(rB + o1);
    float4 xB2 = *(const float4*)(rB + o2);

    for (int k = 0; k < cnt; k += 2) {
      // prefetch next pair (clamped; tail re-reads hit L1)
      const int pA = (k + 2 < cnt) ? k + 2 : cnt - 1;
      const int pB = (k + 3 < cnt) ? k + 3 : cnt - 1;
      const float* fA = wbase + (size_t)pA * 4 * H_SZ;
      const float* fB = wbase + (size_t)pB * 4 * H_SZ;
      const float4 nA0 = *(const float4*)(fA + o0);
      const float4 nA1 = *(const float4*)(fA + o1);
      const float4 nA2 = *(const float4*)(fA + o2);
      const float4 nB0 = *(const float4*)(fB + o0);
      const float4 nB1 = *(const float4*)(fB + o1);
      const float4 nB2 = *(const float4*)(fB + o2);

      // two independent reduce chains, interleaved (pipelined)
      float pa = dot12(xA0, xA1, xA2, q0, q1, q2);
      float pb = dot12(xB0, xB1, xB2, q0, q1, q2);
#pragma unroll
      for (int off = 32; off > 0; off >>= 1) {
        pa += __shfl_xor(pa, off);
        pb += __shfl_xor(pb, off);
      }
      const float sA = pa + qb2;
      const float sB = (k + 1 < cnt) ? pb + qb2 : -INFINITY;  // invalid -> 0 weight

      // single pair-merged online-softmax update
      const float m2 = fmaxf(m, fmaxf(sA, sB));
      const float c = exp2f(m - m2);    // first iter: exp2(-inf)=0
      const float eA = exp2f(sA - m2);
      const float eB = exp2f(sB - m2);  // exp2(-inf)=0 for invalid row
      l = l * c + eA + eB;
      a0.x = fmaf(eA, xA0.x, fmaf(eB, xB0.x, a0.x * c));
      a0.y = fmaf(eA, xA0.y, fmaf(eB, xB0.y, a0.y * c));
      a0.z = fmaf(eA, xA0.z, fmaf(eB, xB0.z, a0.z * c));
      a0.w = fmaf(eA, xA0.w, fmaf(eB, xB0.w, a0.w * c));
      a1.x = fmaf(eA, xA1.x, fmaf(eB, xB1.x, a1.x * c));
      a1.y = fmaf(eA, xA1.y, fmaf(eB, xB1.y, a1.y * c));
      a1.z = fmaf(eA, xA1.z, fmaf(eB, xB1.z, a1.z * c));
      a1.w = fmaf(eA, xA1.w, fmaf(eB, xB1.w, a1.w * c));
      a2.x = fmaf(eA, xA2.x, fmaf(eB, xB2.x, a2.x * c));
      a2.y = fmaf(eA, xA2.y, fmaf(eB, xB2.y, a2.y * c));
      a2.z = fmaf(eA, xA2.z, fmaf(eB, xB2.z, a2.z * c));
      a2.w = fmaf(eA, xA2.w, fmaf(eB, xB2.w, a2.w * c));
      m = m2;

      xA0 = nA0; xA1 = nA1; xA2 = nA2;
      xB0 = nB0; xB1 = nB1; xB2 = nB2;
    }
  }

  // publish wave-partial state to LDS (transposed: sa[i*256 + w*64 + lane])
  if (lane == 0) { sm[w] = m; sl[w] = l; }
  if (w != 0) {  // wave 0 keeps its state in registers
    const float av[12] = {a0.x, a0.y, a0.z, a0.w, a1.x, a1.y, a1.z, a1.w,
                          a2.x, a2.y, a2.z, a2.w};
#pragma unroll
    for (int i = 0; i < 12; ++i) sa[i * 256 + w * 64 + lane] = av[i];
  }
  __syncthreads();
  if (w != 0) return;

  // wave 0: cross-wave merge, base-2 domain (M finite: wave 0 owns row 0)
  const float M = fmaxf(fmaxf(sm[0], sm[1]), fmaxf(sm[2], sm[3]));
  const float c0 = exp2f(sm[0] - M), c1 = exp2f(sm[1] - M);
  const float c2 = exp2f(sm[2] - M), c3 = exp2f(sm[3] - M);
  const float L = sl[0] * c0 + sl[1] * c1 + sl[2] * c2 + sl[3] * c3;
  const float inv = 1.f / L;

  float e[12] = {a0.x, a0.y, a0.z, a0.w, a1.x, a1.y, a1.z, a1.w,
                 a2.x, a2.y, a2.z, a2.w};
#pragma unroll
  for (int i = 0; i < 12; ++i) {
    e[i] = (e[i] * c0 + sa[i * 256 + 64 + lane] * c1 +
            sa[i * 256 + 128 + lane] * c2 + sa[i * 256 + 192 + lane] * c3) * inv;
  }

  // epilogue: dots with both wm_w halves (same chunked offsets)
  const float4 w10 = *(const float4*)(wmw + o0);
  const float4 w11 = *(const float4*)(wmw + o1);
  const float4 w12 = *(const float4*)(wmw + o2);
  const float4 w20 = *(const float4*)(wmw + H_SZ + o0);
  const float4 w21 = *(const float4*)(wmw + H_SZ + o1);
  const float4 w22 = *(const float4*)(wmw + H_SZ + o2);
  float p1 = e[0] * w10.x + e[1] * w10.y + e[2] * w10.z + e[3] * w10.w
           + e[4] * w11.x + e[5] * w11.y + e[6] * w11.z + e[7] * w11.w
           + e[8] * w12.x + e[9] * w12.y + e[10] * w12.z + e[11] * w12.w;
  float p2 = e[0] * w20.x + e[1] * w20.y + e[2] * w20.z + e[3] * w20.w
           + e[4] * w21.x + e[5] * w21.y + e[6] * w21.z + e[7] * w21.w
           + e[8] * w22.x + e[9] * w22.y + e[10] * w22.z + e[11] * w22.w;
#pragma unroll
  for (int off = 32; off > 0; off >>= 1) {
    p1 += __shfl_xor(p1, off);
    p2 += __shfl_xor(p2, off);
  }
  if (lane == 0) {
    d1[b] = p1;
    d2[b] = p2;
  }
}

// ---------------------------------------------------------------------------
// Kernel 2: logits[q] = (d1[cni[npt[q]]] + d2[npi[q]] + wm_b) / TEMP ; pos flag
// ---------------------------------------------------------------------------
__global__ __launch_bounds__(256) void logits_kernel(
    const float* __restrict__ d1, const float* __restrict__ d2,
    const float* __restrict__ wmb,
    const int* __restrict__ npi, const int* __restrict__ cni,
    const int* __restrict__ npt, const int* __restrict__ labels,
    float* __restrict__ logits, int* __restrict__ pos) {
  const int q = blockIdx.x * 256 + threadIdx.x;
  if (q >= Q_SZ) return;
  const int ty = npt[q];
  const float sims = d1[cni[ty]] + d2[npi[q]] + wmb[0];
  logits[q] = sims / 0.1f;            // match reference's division by TEMP
  pos[q] = (labels[q] == 1) ? 1 : 0;  // labels is [Q,1]
}

// ---------------------------------------------------------------------------
// Kernel 3: per-segment LSE terms. One block per segment s; scans all Q
// (logits/npt/pos are L2-resident). Two passes: max, then sums.
// ---------------------------------------------------------------------------
__global__ __launch_bounds__(256) void segment_kernel(
    const float* __restrict__ logits, const int* __restrict__ npt,
    const int* __restrict__ pos,
    float* __restrict__ seg_term, float* __restrict__ seg_has) {
  const int s = blockIdx.x;
  const int t = threadIdx.x;
  const int lane = t & 63, wid = t >> 6;
  __shared__ float rg[4], rp[4], sa4[4], sp4[4], cp4[4];

  float gmax = -INFINITY, pmax = -INFINITY;
  for (int q = t; q < Q_SZ; q += 256) {
    if (npt[q] == s) {
      const float lg = logits[q];
      gmax = fmaxf(gmax, lg);
      if (pos[q]) pmax = fmaxf(pmax, lg);
    }
  }
#pragma unroll
  for (int off = 32; off > 0; off >>= 1) {
    gmax = fmaxf(gmax, __shfl_xor(gmax, off));
    pmax = fmaxf(pmax, __shfl_xor(pmax, off));
  }
  if (lane == 0) { rg[wid] = gmax; rp[wid] = pmax; }
  __syncthreads();
  gmax = fmaxf(fmaxf(rg[0], rg[1]), fmaxf(rg[2], rg[3]));
  pmax = fmaxf(fmaxf(rp[0], rp[1]), fmaxf(rp[2], rp[3]));
  const float gmaxs = (gmax == -INFINITY) ? 0.f : gmax;
  const float pmaxs = (pmax == -INFINITY) ? 0.f : pmax;

  float sa = 0.f, sp = 0.f, cnt = 0.f;
  for (int q = t; q < Q_SZ; q += 256) {
    if (npt[q] == s) {
      const float lg = logits[q];
      sa += expf(lg - gmaxs);
      if (pos[q]) { sp += expf(lg - pmaxs); cnt += 1.f; }
    }
  }
#pragma unroll
  for (int off = 32; off > 0; off >>= 1) {
    sa += __shfl_xor(sa, off);
    sp += __shfl_xor(sp, off);
    cnt += __shfl_xor(cnt, off);
  }
  if (lane == 0) { sa4[wid] = sa; sp4[wid] = sp; cp4[wid] = cnt; }
  __syncthreads();
  if (t == 0) {
    sa = sa4[0] + sa4[1] + sa4[2] + sa4[3];
    sp = sp4[0] + sp4[1] + sp4[2] + sp4[3];
    cnt = cp4[0] + cp4[1] + cp4[2] + cp4[3];
    const bool haspos = cnt > 0.f;
    float term = 0.f;
    if (haspos) term = (logf(sa) + gmaxs) - (logf(sp) + pmaxs);
    seg_term[s] = term;
    seg_has[s] = haspos ? 1.f : 0.f;
  }
}

// ---------------------------------------------------------------------------
// Kernel 4: loss = sum(term) / max(sum(has), 1)
// ---------------------------------------------------------------------------
__global__ __launch_bounds__(256) void finalize_kernel(
    const float* __restrict__ seg_term, const float* __restrict__ seg_has,
    float* __restrict__ out) {
  const int t = threadIdx.x;
  const int lane = t & 63, wid = t >> 6;
  __shared__ float rt[4], rh[4];
  float v = seg_term[t];
  float h = seg_has[t];
#pragma unroll
  for (int off = 32; off > 0; off >>= 1) {
    v += __shfl_xor(v, off);
    h += __shfl_xor(h, off);
  }
  if (lane == 0) { rt[wid] = v; rh[wid] = h; }
  __syncthreads();
  if (t == 0) {
    const float total = rt[0] + rt[1] + rt[2] + rt[3];
    const float nv = rh[0] + rh[1] + rh[2] + rh[3];
    out[0] = total / fmaxf(nv, 1.f);
  }
}

extern "C" void kernel_launch(void* const* d_in, const int* in_sizes, int n_in,
                              void* d_out, int out_size, void* d_ws, size_t ws_size,
                              hipStream_t stream) {
  const float* padded  = (const float*)d_in[0];
  const float* qw      = (const float*)d_in[1];
  const float* qb      = (const float*)d_in[2];
  const float* wmw     = (const float*)d_in[3];
  const float* wmb     = (const float*)d_in[4];
  const int*   lengths = (const int*)d_in[5];
  const int*   npi     = (const int*)d_in[6];
  const int*   cni     = (const int*)d_in[7];
  const int*   npt     = (const int*)d_in[8];
  const int*   labels  = (const int*)d_in[9];
  float* out = (float*)d_out;

  // workspace layout (all fully written before read each call)
  float* d1       = (float*)d_ws;          // B
  float* d2       = d1 + B_SZ;             // B
  float* logits   = d2 + B_SZ;             // Q
  int*   pos      = (int*)(logits + Q_SZ); // Q
  float* seg_term = (float*)(pos + Q_SZ);  // S
  float* seg_has  = seg_term + S_SZ;       // S

  merge_dots_kernel<<<B_SZ, 256, 0, stream>>>(padded, qw, qb, wmw, lengths, d1, d2);
  logits_kernel<<<Q_SZ / 256, 256, 0, stream>>>(d1, d2, wmb, npi, cni, npt, labels,
                                                logits, pos);
  segment_kernel<<<S_SZ, 256, 0, stream>>>(logits, npt, pos, seg_term, seg_has);
  finalize_kernel<<<1, 256, 0, stream>>>(seg_term, seg_has, out);
}